// Round 1
// baseline (271.851 us; speedup 1.0000x reference)
//
#include <hip/hip_runtime.h>
#include <math.h>

// ---------------- complex helpers ----------------
__device__ __forceinline__ float2 cmul(float2 a, float2 b) {
    return make_float2(a.x * b.x - a.y * b.y, a.x * b.y + a.y * b.x);
}
__device__ __forceinline__ float2 cadd(float2 a, float2 b) {
    return make_float2(a.x + b.x, a.y + b.y);
}

// ================= Kernel A: fused conv1+pool+conv2+pool+avgpool =================
// One block per batch element. LDS: 66x66 input halo tile + 8x34x34 conv1-pooled halo tile.
__global__ __launch_bounds__(256, 2)
void fused_cnn_kernel(const float* __restrict__ X,
                      const float* __restrict__ W1, const float* __restrict__ B1,
                      const float* __restrict__ W2, const float* __restrict__ B2,
                      float* __restrict__ pooled)
{
    const int b = blockIdx.x;
    const int t = threadIdx.x;
    __shared__ float xin[66 * 66];      // padded 64x64 input
    __shared__ float h1[8 * 34 * 34];   // padded 8x32x32 conv1+relu+pool output
    __shared__ float red[16 * 4];

    // ---- stage input with zero halo ----
    const float* xb = X + (size_t)b * (64 * 64);
    for (int idx = t; idx < 66 * 66; idx += 256) {
        int y = idx / 66, x = idx - y * 66;
        float v = 0.f;
        if (y >= 1 && y <= 64 && x >= 1 && x <= 64)
            v = xb[(y - 1) * 64 + (x - 1)];
        xin[idx] = v;
    }
    // zero h1 (halo must be zero; interior overwritten)
    for (int idx = t; idx < 8 * 34 * 34; idx += 256) h1[idx] = 0.f;
    __syncthreads();

    // ---- conv1 + relu + maxpool2: 8 oc, 32x32 pool cells, 4 cells/thread ----
    for (int cell = t; cell < 1024; cell += 256) {
        int py = cell >> 5, px = cell & 31;
        int y0 = 2 * py, x0 = 2 * px;   // halo coords of top-left tap
        float win[4][4];
        #pragma unroll
        for (int r = 0; r < 4; ++r)
            #pragma unroll
            for (int c = 0; c < 4; ++c)
                win[r][c] = xin[(y0 + r) * 66 + (x0 + c)];
        #pragma unroll
        for (int oc = 0; oc < 8; ++oc) {
            float bb = B1[oc];
            float a00 = bb, a01 = bb, a10 = bb, a11 = bb;
            #pragma unroll
            for (int ky = 0; ky < 3; ++ky)
                #pragma unroll
                for (int kx = 0; kx < 3; ++kx) {
                    float w = W1[oc * 9 + ky * 3 + kx];
                    a00 = fmaf(win[ky][kx],         w, a00);
                    a01 = fmaf(win[ky][kx + 1],     w, a01);
                    a10 = fmaf(win[ky + 1][kx],     w, a10);
                    a11 = fmaf(win[ky + 1][kx + 1], w, a11);
                }
            float m = fmaxf(fmaxf(a00, a01), fmaxf(a10, a11));
            h1[oc * (34 * 34) + (py + 1) * 34 + (px + 1)] = fmaxf(m, 0.f);
        }
    }
    __syncthreads();

    // ---- conv2 + relu + maxpool2 + mean: 16 oc, 16x16 cells = 256 threads ----
    const int py = t >> 4, px = t & 15;
    const int y0 = 2 * py, x0 = 2 * px;
    const int lane = t & 63, wid = t >> 6;

    for (int g = 0; g < 4; ++g) {        // oc groups of 4 (runtime loop: code size)
        float acc[4][4];
        #pragma unroll
        for (int o = 0; o < 4; ++o) {
            float bb = B2[g * 4 + o];
            acc[o][0] = bb; acc[o][1] = bb; acc[o][2] = bb; acc[o][3] = bb;
        }
        for (int ic = 0; ic < 8; ++ic) {
            float win[4][4];
            #pragma unroll
            for (int r = 0; r < 4; ++r)
                #pragma unroll
                for (int c = 0; c < 4; ++c)
                    win[r][c] = h1[ic * (34 * 34) + (y0 + r) * 34 + (x0 + c)];
            #pragma unroll
            for (int o = 0; o < 4; ++o) {
                const float* wp = W2 + (size_t)(g * 4 + o) * 72 + ic * 9;
                #pragma unroll
                for (int ky = 0; ky < 3; ++ky)
                    #pragma unroll
                    for (int kx = 0; kx < 3; ++kx) {
                        float w = wp[ky * 3 + kx];
                        acc[o][0] = fmaf(win[ky][kx],         w, acc[o][0]);
                        acc[o][1] = fmaf(win[ky][kx + 1],     w, acc[o][1]);
                        acc[o][2] = fmaf(win[ky + 1][kx],     w, acc[o][2]);
                        acc[o][3] = fmaf(win[ky + 1][kx + 1], w, acc[o][3]);
                    }
            }
        }
        #pragma unroll
        for (int o = 0; o < 4; ++o) {
            float m = fmaxf(fmaxf(acc[o][0], acc[o][1]), fmaxf(acc[o][2], acc[o][3]));
            float v = fmaxf(m, 0.f);
            #pragma unroll
            for (int off = 32; off > 0; off >>= 1)
                v += __shfl_down(v, off, 64);
            if (lane == 0) red[(g * 4 + o) * 4 + wid] = v;
        }
    }
    __syncthreads();
    if (t < 16) {
        float s = red[t * 4] + red[t * 4 + 1] + red[t * 4 + 2] + red[t * 4 + 3];
        pooled[(size_t)b * 16 + t] = s * (1.0f / 256.0f);
    }
}

// ================= Kernel B: MT19937 op-gen + compose 16x16 unitary =================
__global__ void build_unitary_kernel(const float* __restrict__ rl, const float* __restrict__ qp,
                                     float2* __restrict__ Uout)
{
    __shared__ unsigned mtbuf[624];
    __shared__ int opT[57], opA[57], opB[57];
    __shared__ float ang[57];
    __shared__ float2 U[16][16];
    const int t = threadIdx.x;   // 256 threads

    if (t == 0) {
        // ---- numpy legacy MT19937, seed 42 ----
        unsigned* mt = mtbuf;
        mt[0] = 42u;
        for (int i = 1; i < 624; ++i)
            mt[i] = 1812433253u * (mt[i - 1] ^ (mt[i - 1] >> 30)) + (unsigned)i;
        int mti = 624;
        auto nextu = [&]() -> unsigned {
            if (mti >= 624) {
                for (int i = 0; i < 624; ++i) {
                    unsigned y = (mt[i] & 0x80000000u) | (mt[(i + 1) % 624] & 0x7fffffffu);
                    mt[i] = mt[(i + 397) % 624] ^ (y >> 1) ^ ((y & 1u) ? 2567483615u : 0u);
                }
                mti = 0;
            }
            unsigned y = mt[mti++];
            y ^= y >> 11;
            y ^= (y << 7)  & 2636928640u;
            y ^= (y << 15) & 4022730752u;
            y ^= y >> 18;
            return y;
        };
        // ---- RandomLayer spec: replicate RandomState(42) stream ----
        for (int k = 0; k < 50; ++k) {
            unsigned g = nextu() & 3u;                 // randint(4): mask=3, no rejection
            if (g < 3u) {
                unsigned w = nextu() & 3u;             // randint(4)
                opT[k] = (int)g; opA[k] = (int)w; opB[k] = 0;
            } else {
                // choice(4,2,replace=False) == permutation(4)[:2], Fisher-Yates from i=3
                int arr[4] = {0, 1, 2, 3};
                unsigned j3 = nextu() & 3u;            // interval(3): no rejection
                { int tmp = arr[3]; arr[3] = arr[j3]; arr[j3] = tmp; }
                unsigned j2;
                do { j2 = nextu() & 3u; } while (j2 > 2u);   // interval(2): mask=3, reject >2
                { int tmp = arr[2]; arr[2] = arr[j2]; arr[j2] = tmp; }
                unsigned j1 = nextu() & 1u;            // interval(1)
                { int tmp = arr[1]; arr[1] = arr[j1]; arr[j1] = tmp; }
                opT[k] = 3; opA[k] = arr[0]; opB[k] = arr[1];
            }
            ang[k] = rl[k];
        }
        // ---- fixed trainable/const gates ----
        opT[50] = 0; opA[50] = 0; opB[50] = 0; ang[50] = qp[0];   // rx @0
        opT[51] = 1; opA[51] = 1; opB[51] = 0; ang[51] = qp[1];   // ry @1
        opT[52] = 2; opA[52] = 3; opB[52] = 0; ang[52] = qp[2];   // rz @3
        opT[53] = 3; opA[53] = 0; opB[53] = 2; ang[53] = qp[3];   // crx @(0,2)
        opT[54] = 4; opA[54] = 3; opB[54] = 0; ang[54] = 0.f;     // H @3
        opT[55] = 5; opA[55] = 2; opB[55] = 0; ang[55] = 0.f;     // SX @2
        opT[56] = 6; opA[56] = 3; opB[56] = 0; ang[56] = 0.f;     // CNOT @(3,0)
    }
    // init U = I
    U[t >> 4][t & 15] = make_float2(((t >> 4) == (t & 15)) ? 1.f : 0.f, 0.f);
    __syncthreads();

    for (int k = 0; k < 57; ++k) {
        const int ty = opT[k], wa = opA[k], wb = opB[k];
        const float th = ang[k];
        float sh, ch;
        sincosf(0.5f * th, &sh, &ch);
        float2 m00, m01, m10, m11;
        switch (ty) {
            case 0: // rx
            case 3: // crx (inner rx)
                m00 = make_float2(ch, 0.f); m01 = make_float2(0.f, -sh);
                m10 = make_float2(0.f, -sh); m11 = make_float2(ch, 0.f);
                break;
            case 1: // ry
                m00 = make_float2(ch, 0.f); m01 = make_float2(-sh, 0.f);
                m10 = make_float2(sh, 0.f); m11 = make_float2(ch, 0.f);
                break;
            case 2: // rz
                m00 = make_float2(ch, -sh); m01 = make_float2(0.f, 0.f);
                m10 = make_float2(0.f, 0.f); m11 = make_float2(ch, sh);
                break;
            case 4: { // H
                const float r = 0.70710678118654752f;
                m00 = make_float2(r, 0.f); m01 = make_float2(r, 0.f);
                m10 = make_float2(r, 0.f); m11 = make_float2(-r, 0.f);
                break;
            }
            case 5: // SX
                m00 = make_float2(0.5f, 0.5f);  m01 = make_float2(0.5f, -0.5f);
                m10 = make_float2(0.5f, -0.5f); m11 = make_float2(0.5f, 0.5f);
                break;
            default: // 6: CNOT (inner X)
                m00 = make_float2(0.f, 0.f); m01 = make_float2(1.f, 0.f);
                m10 = make_float2(1.f, 0.f); m11 = make_float2(0.f, 0.f);
                break;
        }
        const bool ctrl = (ty == 3 || ty == 6);
        if (!ctrl) {
            const int mask = 8 >> wa;
            if (t < 128) {
                int col = t & 15, p = t >> 4;   // 8 pairs
                int lowmask = mask - 1;
                int i0 = ((p & ~lowmask) << 1) | (p & lowmask);
                int i1 = i0 | mask;
                float2 a = U[i0][col], bb = U[i1][col];
                U[i0][col] = cadd(cmul(m00, a), cmul(m01, bb));
                U[i1][col] = cadd(cmul(m10, a), cmul(m11, bb));
            }
        } else {
            const int cm = 8 >> wa, tm = 8 >> wb;
            if (t < 64) {
                int col = t & 15, p = t >> 4;   // 4 pairs (control bit = 1)
                int i0 = cm, pp = p;
                #pragma unroll
                for (int bit = 0; bit < 4; ++bit) {
                    int m = 1 << bit;
                    if (m == cm || m == tm) continue;
                    if (pp & 1) i0 |= m;
                    pp >>= 1;
                }
                int i1 = i0 | tm;
                float2 a = U[i0][col], bb = U[i1][col];
                U[i0][col] = cadd(cmul(m00, a), cmul(m01, bb));
                U[i1][col] = cadd(cmul(m10, a), cmul(m11, bb));
            }
        }
        __syncthreads();
    }
    Uout[t] = U[t >> 4][t & 15];
}

// ================= Kernel C: per-batch product state -> U s -> <Z> -> head+BN =================
__global__ __launch_bounds__(256)
void quantum_head_kernel(const float* __restrict__ pooled, const float2* __restrict__ Uin,
                         const float* __restrict__ head_w, const float* __restrict__ head_b,
                         const float* __restrict__ bn_g, const float* __restrict__ bn_b,
                         const float* __restrict__ bn_m, const float* __restrict__ bn_v,
                         float* __restrict__ out)
{
    __shared__ float2 U[256];
    const int t = threadIdx.x;
    U[t] = Uin[t];
    __syncthreads();
    const int b = blockIdx.x * 256 + t;

    // encoder product state: per wire v = Ry(p12+w) Rx(p8+w) Rz(p4+w) Ry(pw) |0>
    float2 v0[4], v1[4];
    #pragma unroll
    for (int w = 0; w < 4; ++w) {
        float a  = pooled[(size_t)b * 16 + w];
        float bz = pooled[(size_t)b * 16 + 4 + w];
        float gx = pooled[(size_t)b * 16 + 8 + w];
        float dl = pooled[(size_t)b * 16 + 12 + w];
        float sa, ca, sb, cb, sg, cg, sd, cd;
        sincosf(0.5f * a,  &sa, &ca);
        sincosf(0.5f * bz, &sb, &cb);
        sincosf(0.5f * gx, &sg, &cg);
        sincosf(0.5f * dl, &sd, &cd);
        // Ry(a)|0> = (ca, sa); apply Rz(b): phases e^{-ib/2}, e^{ib/2}
        float2 u0 = make_float2(ca * cb, -ca * sb);
        float2 u1 = make_float2(sa * cb,  sa * sb);
        // Rx(g): w0 = cg*u0 - i sg*u1 ; w1 = -i sg*u0 + cg*u1
        float2 w0 = make_float2(cg * u0.x + sg * u1.y, cg * u0.y - sg * u1.x);
        float2 w1 = make_float2(sg * u0.y + cg * u1.x, -sg * u0.x + cg * u1.y);
        // Ry(d)
        v0[w] = make_float2(cd * w0.x - sd * w1.x, cd * w0.y - sd * w1.y);
        v1[w] = make_float2(sd * w0.x + cd * w1.x, sd * w0.y + cd * w1.y);
    }
    float2 s01[4], s23[4], s[16];
    s01[0] = cmul(v0[0], v0[1]); s01[1] = cmul(v0[0], v1[1]);
    s01[2] = cmul(v1[0], v0[1]); s01[3] = cmul(v1[0], v1[1]);
    s23[0] = cmul(v0[2], v0[3]); s23[1] = cmul(v0[2], v1[3]);
    s23[2] = cmul(v1[2], v0[3]); s23[3] = cmul(v1[2], v1[3]);
    #pragma unroll
    for (int i = 0; i < 4; ++i)
        #pragma unroll
        for (int j = 0; j < 4; ++j)
            s[i * 4 + j] = cmul(s01[i], s23[j]);

    float fz0 = 0.f, fz1 = 0.f, fz2 = 0.f, fz3 = 0.f;
    #pragma unroll
    for (int i = 0; i < 16; ++i) {
        float2 acc = make_float2(0.f, 0.f);
        #pragma unroll
        for (int j = 0; j < 16; ++j)
            acc = cadd(acc, cmul(U[i * 16 + j], s[j]));
        float pr = acc.x * acc.x + acc.y * acc.y;
        fz0 += ((i >> 3) & 1) ? -pr : pr;
        fz1 += ((i >> 2) & 1) ? -pr : pr;
        fz2 += ((i >> 1) & 1) ? -pr : pr;
        fz3 += (i & 1) ? -pr : pr;
    }
    float o = head_b[0];
    o = fmaf(fz0, head_w[0], o);
    o = fmaf(fz1, head_w[1], o);
    o = fmaf(fz2, head_w[2], o);
    o = fmaf(fz3, head_w[3], o);
    o = bn_g[0] * (o - bn_m[0]) / sqrtf(bn_v[0] + 1e-5f) + bn_b[0];
    out[b] = o;
}

extern "C" void kernel_launch(void* const* d_in, const int* in_sizes, int n_in,
                              void* d_out, int out_size, void* d_ws, size_t ws_size,
                              hipStream_t stream)
{
    const float* X  = (const float*)d_in[0];
    const float* W1 = (const float*)d_in[1];
    const float* B1 = (const float*)d_in[2];
    const float* W2 = (const float*)d_in[3];
    const float* B2 = (const float*)d_in[4];
    const float* RL = (const float*)d_in[5];
    const float* QP = (const float*)d_in[6];
    const float* HW = (const float*)d_in[7];
    const float* HB = (const float*)d_in[8];
    const float* BG = (const float*)d_in[9];
    const float* BB = (const float*)d_in[10];
    const float* BM = (const float*)d_in[11];
    const float* BV = (const float*)d_in[12];
    float* out = (float*)d_out;

    float*  pooled = (float*)d_ws;                          // 1024*16 floats = 64 KiB
    float2* U      = (float2*)((char*)d_ws + 1024 * 16 * 4); // 256 float2 = 2 KiB

    fused_cnn_kernel<<<1024, 256, 0, stream>>>(X, W1, B1, W2, B2, pooled);
    build_unitary_kernel<<<1, 256, 0, stream>>>(RL, QP, U);
    quantum_head_kernel<<<4, 256, 0, stream>>>(pooled, U, HW, HB, BG, BB, BM, BV, out);
}

// Round 2
// 111.431 us; speedup vs baseline: 2.4396x; 2.4396x over previous
//
#include <hip/hip_runtime.h>
#include <math.h>

// ---------------- complex helpers ----------------
__device__ __forceinline__ float2 cmul(float2 a, float2 b) {
    return make_float2(a.x * b.x - a.y * b.y, a.x * b.y + a.y * b.x);
}
__device__ __forceinline__ float2 cadd(float2 a, float2 b) {
    return make_float2(a.x + b.x, a.y + b.y);
}

struct OpsSpec {
    int ty[57];
    int wa[57];
    int wb[57];
};

// ================= host: numpy-legacy MT19937 (RandomState(42)) op generation =================
// Verified bit-exact in Round 1 (on-device version passed with absmax 0.0).
static void gen_ops_host(OpsSpec& S) {
    unsigned mt[624];
    mt[0] = 42u;
    for (int i = 1; i < 624; ++i)
        mt[i] = 1812433253u * (mt[i - 1] ^ (mt[i - 1] >> 30)) + (unsigned)i;
    int mti = 624;
    auto nextu = [&]() -> unsigned {
        if (mti >= 624) {
            for (int i = 0; i < 624; ++i) {
                unsigned y = (mt[i] & 0x80000000u) | (mt[(i + 1) % 624] & 0x7fffffffu);
                mt[i] = mt[(i + 397) % 624] ^ (y >> 1) ^ ((y & 1u) ? 2567483615u : 0u);
            }
            mti = 0;
        }
        unsigned y = mt[mti++];
        y ^= y >> 11;
        y ^= (y << 7)  & 2636928640u;
        y ^= (y << 15) & 4022730752u;
        y ^= y >> 18;
        return y;
    };
    for (int k = 0; k < 50; ++k) {
        unsigned g = nextu() & 3u;              // randint(4)
        if (g < 3u) {
            unsigned w = nextu() & 3u;          // randint(4)
            S.ty[k] = (int)g; S.wa[k] = (int)w; S.wb[k] = 0;
        } else {
            // choice(4,2,replace=False) == permutation(4)[:2], Fisher-Yates from i=3
            int arr[4] = {0, 1, 2, 3};
            unsigned j3 = nextu() & 3u;                         // interval(3)
            { int tmp = arr[3]; arr[3] = arr[j3]; arr[j3] = tmp; }
            unsigned j2;
            do { j2 = nextu() & 3u; } while (j2 > 2u);          // interval(2), reject
            { int tmp = arr[2]; arr[2] = arr[j2]; arr[j2] = tmp; }
            unsigned j1 = nextu() & 1u;                         // interval(1)
            { int tmp = arr[1]; arr[1] = arr[j1]; arr[j1] = tmp; }
            S.ty[k] = 3; S.wa[k] = arr[0]; S.wb[k] = arr[1];
        }
    }
    // fixed trainable/const gates
    S.ty[50] = 0; S.wa[50] = 0; S.wb[50] = 0;   // rx  @0  (qp[0])
    S.ty[51] = 1; S.wa[51] = 1; S.wb[51] = 0;   // ry  @1  (qp[1])
    S.ty[52] = 2; S.wa[52] = 3; S.wb[52] = 0;   // rz  @3  (qp[2])
    S.ty[53] = 3; S.wa[53] = 0; S.wb[53] = 2;   // crx @(0,2) (qp[3])
    S.ty[54] = 4; S.wa[54] = 3; S.wb[54] = 0;   // H   @3
    S.ty[55] = 5; S.wa[55] = 2; S.wb[55] = 0;   // SX  @2
    S.ty[56] = 6; S.wa[56] = 3; S.wb[56] = 0;   // CNOT@(3,0)
}

// ================= Kernel U: compose 16x16 unitary from host-provided op list =================
__global__ void unitary_kernel(OpsSpec S, const float* __restrict__ rl,
                               const float* __restrict__ qp, float2* __restrict__ Uout)
{
    __shared__ float2 U[16][16];
    const int t = threadIdx.x;   // 256 threads
    U[t >> 4][t & 15] = make_float2(((t >> 4) == (t & 15)) ? 1.f : 0.f, 0.f);
    __syncthreads();

    for (int k = 0; k < 57; ++k) {
        const int ty = S.ty[k], wa = S.wa[k], wb = S.wb[k];
        const float th = (k < 50) ? rl[k] : ((k < 54) ? qp[k - 50] : 0.f);
        float sh, ch;
        sincosf(0.5f * th, &sh, &ch);
        float2 m00, m01, m10, m11;
        switch (ty) {
            case 0: // rx
            case 3: // crx (inner rx)
                m00 = make_float2(ch, 0.f); m01 = make_float2(0.f, -sh);
                m10 = make_float2(0.f, -sh); m11 = make_float2(ch, 0.f);
                break;
            case 1: // ry
                m00 = make_float2(ch, 0.f); m01 = make_float2(-sh, 0.f);
                m10 = make_float2(sh, 0.f); m11 = make_float2(ch, 0.f);
                break;
            case 2: // rz
                m00 = make_float2(ch, -sh); m01 = make_float2(0.f, 0.f);
                m10 = make_float2(0.f, 0.f); m11 = make_float2(ch, sh);
                break;
            case 4: { // H
                const float r = 0.70710678118654752f;
                m00 = make_float2(r, 0.f); m01 = make_float2(r, 0.f);
                m10 = make_float2(r, 0.f); m11 = make_float2(-r, 0.f);
                break;
            }
            case 5: // SX
                m00 = make_float2(0.5f, 0.5f);  m01 = make_float2(0.5f, -0.5f);
                m10 = make_float2(0.5f, -0.5f); m11 = make_float2(0.5f, 0.5f);
                break;
            default: // 6: CNOT (inner X)
                m00 = make_float2(0.f, 0.f); m01 = make_float2(1.f, 0.f);
                m10 = make_float2(1.f, 0.f); m11 = make_float2(0.f, 0.f);
                break;
        }
        const bool ctrl = (ty == 3 || ty == 6);
        if (!ctrl) {
            const int mask = 8 >> wa;
            if (t < 128) {
                int col = t & 15, p = t >> 4;   // 8 pairs
                int lowmask = mask - 1;
                int i0 = ((p & ~lowmask) << 1) | (p & lowmask);
                int i1 = i0 | mask;
                float2 a = U[i0][col], bb = U[i1][col];
                U[i0][col] = cadd(cmul(m00, a), cmul(m01, bb));
                U[i1][col] = cadd(cmul(m10, a), cmul(m11, bb));
            }
        } else {
            const int cm = 8 >> wa, tm = 8 >> wb;
            if (t < 64) {
                int col = t & 15, p = t >> 4;   // 4 pairs (control bit = 1)
                int i0 = cm, pp = p;
                #pragma unroll
                for (int bit = 0; bit < 4; ++bit) {
                    int m = 1 << bit;
                    if (m == cm || m == tm) continue;
                    if (pp & 1) i0 |= m;
                    pp >>= 1;
                }
                int i1 = i0 | tm;
                float2 a = U[i0][col], bb = U[i1][col];
                U[i0][col] = cadd(cmul(m00, a), cmul(m01, bb));
                U[i1][col] = cadd(cmul(m10, a), cmul(m11, bb));
            }
        }
        __syncthreads();
    }
    Uout[t] = U[t >> 4][t & 15];
}

// ================= Kernel 1: conv1 + relu + maxpool2 -> global =================
__global__ __launch_bounds__(256, 8)
void conv1_kernel(const float* __restrict__ X, const float* __restrict__ W1,
                  const float* __restrict__ B1, float* __restrict__ h1g)
{
    const int b = blockIdx.x, t = threadIdx.x;
    __shared__ float xin[66 * 66];
    const float* xb = X + (size_t)b * 4096;
    for (int idx = t; idx < 66 * 66; idx += 256) {
        int y = idx / 66, x = idx - y * 66;
        float v = 0.f;
        if (y >= 1 && y <= 64 && x >= 1 && x <= 64)
            v = xb[(y - 1) * 64 + (x - 1)];
        xin[idx] = v;
    }
    __syncthreads();
    for (int cell = t; cell < 1024; cell += 256) {
        int py = cell >> 5, px = cell & 31;
        int y0 = 2 * py, x0 = 2 * px;
        float win[4][4];
        #pragma unroll
        for (int r = 0; r < 4; ++r) {
            float2 p0 = *(const float2*)&xin[(y0 + r) * 66 + x0];
            float2 p1 = *(const float2*)&xin[(y0 + r) * 66 + x0 + 2];
            win[r][0] = p0.x; win[r][1] = p0.y; win[r][2] = p1.x; win[r][3] = p1.y;
        }
        #pragma unroll
        for (int oc = 0; oc < 8; ++oc) {
            float bb = B1[oc];
            float a00 = bb, a01 = bb, a10 = bb, a11 = bb;
            #pragma unroll
            for (int ky = 0; ky < 3; ++ky)
                #pragma unroll
                for (int kx = 0; kx < 3; ++kx) {
                    float w = W1[oc * 9 + ky * 3 + kx];
                    a00 = fmaf(win[ky][kx],         w, a00);
                    a01 = fmaf(win[ky][kx + 1],     w, a01);
                    a10 = fmaf(win[ky + 1][kx],     w, a10);
                    a11 = fmaf(win[ky + 1][kx + 1], w, a11);
                }
            float m = fmaxf(fmaxf(a00, a01), fmaxf(a10, a11));
            h1g[((size_t)b * 8 + oc) * 1024 + cell] = fmaxf(m, 0.f);
        }
    }
}

// ================= Kernel 2: conv2 + relu + maxpool2 + avg + quantum head =================
__global__ __launch_bounds__(256, 4)
void conv2_head_kernel(const float* __restrict__ h1g, const float* __restrict__ W2,
                       const float* __restrict__ B2, const float2* __restrict__ Ug,
                       const float* __restrict__ head_w, const float* __restrict__ head_b,
                       const float* __restrict__ bn_g, const float* __restrict__ bn_b,
                       const float* __restrict__ bn_m, const float* __restrict__ bn_v,
                       float* __restrict__ out)
{
    const int b = blockIdx.x, t = threadIdx.x;
    __shared__ float h1s[8 * 34 * 34];   // halo-padded conv1-pooled maps
    __shared__ float2 Ul[256];
    __shared__ float red[16 * 4];
    __shared__ float pool16[16];

    Ul[t] = Ug[t];
    for (int i = t; i < 8 * 34 * 34; i += 256) h1s[i] = 0.f;
    __syncthreads();
    for (int i = t; i < 8192; i += 256) {
        int oc = i >> 10, cell = i & 1023;
        int y = cell >> 5, x = cell & 31;
        h1s[oc * 1156 + (y + 1) * 34 + (x + 1)] = h1g[(size_t)b * 8192 + i];
    }
    __syncthreads();

    const int py = t >> 4, px = t & 15;
    const int y0 = 2 * py, x0 = 2 * px;
    const int lane = t & 63, wid = t >> 6;

    for (int g = 0; g < 2; ++g) {
        float acc[8][4];
        #pragma unroll
        for (int o = 0; o < 8; ++o) {
            float bb = B2[g * 8 + o];
            acc[o][0] = bb; acc[o][1] = bb; acc[o][2] = bb; acc[o][3] = bb;
        }
        for (int ic = 0; ic < 8; ++ic) {
            const int base = ic * 1156 + y0 * 34 + x0;
            float win[4][4];
            #pragma unroll
            for (int r = 0; r < 4; ++r) {
                float2 p0 = *(const float2*)&h1s[base + r * 34];
                float2 p1 = *(const float2*)&h1s[base + r * 34 + 2];
                win[r][0] = p0.x; win[r][1] = p0.y; win[r][2] = p1.x; win[r][3] = p1.y;
            }
            #pragma unroll
            for (int o = 0; o < 8; ++o) {
                const float* wp = W2 + (size_t)((g * 8 + o) * 8 + ic) * 9;
                #pragma unroll
                for (int ky = 0; ky < 3; ++ky)
                    #pragma unroll
                    for (int kx = 0; kx < 3; ++kx) {
                        float w = wp[ky * 3 + kx];
                        acc[o][0] = fmaf(win[ky][kx],         w, acc[o][0]);
                        acc[o][1] = fmaf(win[ky][kx + 1],     w, acc[o][1]);
                        acc[o][2] = fmaf(win[ky + 1][kx],     w, acc[o][2]);
                        acc[o][3] = fmaf(win[ky + 1][kx + 1], w, acc[o][3]);
                    }
            }
        }
        #pragma unroll
        for (int o = 0; o < 8; ++o) {
            float m = fmaxf(fmaxf(acc[o][0], acc[o][1]), fmaxf(acc[o][2], acc[o][3]));
            float v = fmaxf(m, 0.f);
            #pragma unroll
            for (int off = 32; off > 0; off >>= 1)
                v += __shfl_down(v, off, 64);
            if (lane == 0) red[(g * 8 + o) * 4 + wid] = v;
        }
    }
    __syncthreads();
    if (t < 16)
        pool16[t] = (red[t * 4] + red[t * 4 + 1] + red[t * 4 + 2] + red[t * 4 + 3]) * (1.0f / 256.0f);
    __syncthreads();

    // ---- quantum head: product state from encoder, amplitude row t, <Z>, linear+BN ----
    if (t < 16) {
        float2 v0[4], v1[4];
        #pragma unroll
        for (int w = 0; w < 4; ++w) {
            float a  = pool16[w];
            float bz = pool16[4 + w];
            float gx = pool16[8 + w];
            float dl = pool16[12 + w];
            float sa, ca, sb, cb, sg, cg, sd, cd;
            sincosf(0.5f * a,  &sa, &ca);
            sincosf(0.5f * bz, &sb, &cb);
            sincosf(0.5f * gx, &sg, &cg);
            sincosf(0.5f * dl, &sd, &cd);
            float2 u0 = make_float2(ca * cb, -ca * sb);
            float2 u1 = make_float2(sa * cb,  sa * sb);
            float2 w0 = make_float2(cg * u0.x + sg * u1.y, cg * u0.y - sg * u1.x);
            float2 w1 = make_float2(sg * u0.y + cg * u1.x, -sg * u0.x + cg * u1.y);
            v0[w] = make_float2(cd * w0.x - sd * w1.x, cd * w0.y - sd * w1.y);
            v1[w] = make_float2(sd * w0.x + cd * w1.x, sd * w0.y + cd * w1.y);
        }
        float2 s01[4], s23[4];
        s01[0] = cmul(v0[0], v0[1]); s01[1] = cmul(v0[0], v1[1]);
        s01[2] = cmul(v1[0], v0[1]); s01[3] = cmul(v1[0], v1[1]);
        s23[0] = cmul(v0[2], v0[3]); s23[1] = cmul(v0[2], v1[3]);
        s23[2] = cmul(v1[2], v0[3]); s23[3] = cmul(v1[2], v1[3]);
        float2 acc = make_float2(0.f, 0.f);
        #pragma unroll
        for (int i = 0; i < 4; ++i)
            #pragma unroll
            for (int j = 0; j < 4; ++j) {
                float2 sij = cmul(s01[i], s23[j]);
                acc = cadd(acc, cmul(Ul[t * 16 + i * 4 + j], sij));
            }
        float pr = acc.x * acc.x + acc.y * acc.y;
        float fz0 = 0.f, fz1 = 0.f, fz2 = 0.f, fz3 = 0.f;
        #pragma unroll
        for (int i = 0; i < 16; ++i) {
            float p = __shfl(pr, i, 64);
            fz0 += ((i >> 3) & 1) ? -p : p;
            fz1 += ((i >> 2) & 1) ? -p : p;
            fz2 += ((i >> 1) & 1) ? -p : p;
            fz3 += (i & 1) ? -p : p;
        }
        if (t == 0) {
            float o = head_b[0];
            o = fmaf(fz0, head_w[0], o);
            o = fmaf(fz1, head_w[1], o);
            o = fmaf(fz2, head_w[2], o);
            o = fmaf(fz3, head_w[3], o);
            o = bn_g[0] * (o - bn_m[0]) / sqrtf(bn_v[0] + 1e-5f) + bn_b[0];
            out[b] = o;
        }
    }
}

// ================= Fallback path (Round-1 verified kernels, used only if ws too small) =================
__global__ __launch_bounds__(256, 2)
void fused_cnn_kernel(const float* __restrict__ X,
                      const float* __restrict__ W1, const float* __restrict__ B1,
                      const float* __restrict__ W2, const float* __restrict__ B2,
                      float* __restrict__ pooled)
{
    const int b = blockIdx.x;
    const int t = threadIdx.x;
    __shared__ float xin[66 * 66];
    __shared__ float h1[8 * 34 * 34];
    __shared__ float red[16 * 4];

    const float* xb = X + (size_t)b * (64 * 64);
    for (int idx = t; idx < 66 * 66; idx += 256) {
        int y = idx / 66, x = idx - y * 66;
        float v = 0.f;
        if (y >= 1 && y <= 64 && x >= 1 && x <= 64)
            v = xb[(y - 1) * 64 + (x - 1)];
        xin[idx] = v;
    }
    for (int idx = t; idx < 8 * 34 * 34; idx += 256) h1[idx] = 0.f;
    __syncthreads();

    for (int cell = t; cell < 1024; cell += 256) {
        int py = cell >> 5, px = cell & 31;
        int y0 = 2 * py, x0 = 2 * px;
        float win[4][4];
        #pragma unroll
        for (int r = 0; r < 4; ++r)
            #pragma unroll
            for (int c = 0; c < 4; ++c)
                win[r][c] = xin[(y0 + r) * 66 + (x0 + c)];
        #pragma unroll
        for (int oc = 0; oc < 8; ++oc) {
            float bb = B1[oc];
            float a00 = bb, a01 = bb, a10 = bb, a11 = bb;
            #pragma unroll
            for (int ky = 0; ky < 3; ++ky)
                #pragma unroll
                for (int kx = 0; kx < 3; ++kx) {
                    float w = W1[oc * 9 + ky * 3 + kx];
                    a00 = fmaf(win[ky][kx],         w, a00);
                    a01 = fmaf(win[ky][kx + 1],     w, a01);
                    a10 = fmaf(win[ky + 1][kx],     w, a10);
                    a11 = fmaf(win[ky + 1][kx + 1], w, a11);
                }
            float m = fmaxf(fmaxf(a00, a01), fmaxf(a10, a11));
            h1[oc * (34 * 34) + (py + 1) * 34 + (px + 1)] = fmaxf(m, 0.f);
        }
    }
    __syncthreads();

    const int py = t >> 4, px = t & 15;
    const int y0 = 2 * py, x0 = 2 * px;
    const int lane = t & 63, wid = t >> 6;

    for (int g = 0; g < 4; ++g) {
        float acc[4][4];
        #pragma unroll
        for (int o = 0; o < 4; ++o) {
            float bb = B2[g * 4 + o];
            acc[o][0] = bb; acc[o][1] = bb; acc[o][2] = bb; acc[o][3] = bb;
        }
        for (int ic = 0; ic < 8; ++ic) {
            float win[4][4];
            #pragma unroll
            for (int r = 0; r < 4; ++r)
                #pragma unroll
                for (int c = 0; c < 4; ++c)
                    win[r][c] = h1[ic * (34 * 34) + (y0 + r) * 34 + (x0 + c)];
            #pragma unroll
            for (int o = 0; o < 4; ++o) {
                const float* wp = W2 + (size_t)(g * 4 + o) * 72 + ic * 9;
                #pragma unroll
                for (int ky = 0; ky < 3; ++ky)
                    #pragma unroll
                    for (int kx = 0; kx < 3; ++kx) {
                        float w = wp[ky * 3 + kx];
                        acc[o][0] = fmaf(win[ky][kx],         w, acc[o][0]);
                        acc[o][1] = fmaf(win[ky][kx + 1],     w, acc[o][1]);
                        acc[o][2] = fmaf(win[ky + 1][kx],     w, acc[o][2]);
                        acc[o][3] = fmaf(win[ky + 1][kx + 1], w, acc[o][3]);
                    }
            }
        }
        #pragma unroll
        for (int o = 0; o < 4; ++o) {
            float m = fmaxf(fmaxf(acc[o][0], acc[o][1]), fmaxf(acc[o][2], acc[o][3]));
            float v = fmaxf(m, 0.f);
            #pragma unroll
            for (int off = 32; off > 0; off >>= 1)
                v += __shfl_down(v, off, 64);
            if (lane == 0) red[(g * 4 + o) * 4 + wid] = v;
        }
    }
    __syncthreads();
    if (t < 16) {
        float s = red[t * 4] + red[t * 4 + 1] + red[t * 4 + 2] + red[t * 4 + 3];
        pooled[(size_t)b * 16 + t] = s * (1.0f / 256.0f);
    }
}

__global__ __launch_bounds__(256)
void quantum_head_kernel(const float* __restrict__ pooled, const float2* __restrict__ Uin,
                         const float* __restrict__ head_w, const float* __restrict__ head_b,
                         const float* __restrict__ bn_g, const float* __restrict__ bn_b,
                         const float* __restrict__ bn_m, const float* __restrict__ bn_v,
                         float* __restrict__ out)
{
    __shared__ float2 U[256];
    const int t = threadIdx.x;
    U[t] = Uin[t];
    __syncthreads();
    const int b = blockIdx.x * 256 + t;

    float2 v0[4], v1[4];
    #pragma unroll
    for (int w = 0; w < 4; ++w) {
        float a  = pooled[(size_t)b * 16 + w];
        float bz = pooled[(size_t)b * 16 + 4 + w];
        float gx = pooled[(size_t)b * 16 + 8 + w];
        float dl = pooled[(size_t)b * 16 + 12 + w];
        float sa, ca, sb, cb, sg, cg, sd, cd;
        sincosf(0.5f * a,  &sa, &ca);
        sincosf(0.5f * bz, &sb, &cb);
        sincosf(0.5f * gx, &sg, &cg);
        sincosf(0.5f * dl, &sd, &cd);
        float2 u0 = make_float2(ca * cb, -ca * sb);
        float2 u1 = make_float2(sa * cb,  sa * sb);
        float2 w0 = make_float2(cg * u0.x + sg * u1.y, cg * u0.y - sg * u1.x);
        float2 w1 = make_float2(sg * u0.y + cg * u1.x, -sg * u0.x + cg * u1.y);
        v0[w] = make_float2(cd * w0.x - sd * w1.x, cd * w0.y - sd * w1.y);
        v1[w] = make_float2(sd * w0.x + cd * w1.x, sd * w0.y + cd * w1.y);
    }
    float2 s01[4], s23[4], s[16];
    s01[0] = cmul(v0[0], v0[1]); s01[1] = cmul(v0[0], v1[1]);
    s01[2] = cmul(v1[0], v0[1]); s01[3] = cmul(v1[0], v1[1]);
    s23[0] = cmul(v0[2], v0[3]); s23[1] = cmul(v0[2], v1[3]);
    s23[2] = cmul(v1[2], v0[3]); s23[3] = cmul(v1[2], v1[3]);
    #pragma unroll
    for (int i = 0; i < 4; ++i)
        #pragma unroll
        for (int j = 0; j < 4; ++j)
            s[i * 4 + j] = cmul(s01[i], s23[j]);

    float fz0 = 0.f, fz1 = 0.f, fz2 = 0.f, fz3 = 0.f;
    #pragma unroll
    for (int i = 0; i < 16; ++i) {
        float2 acc = make_float2(0.f, 0.f);
        #pragma unroll
        for (int j = 0; j < 16; ++j)
            acc = cadd(acc, cmul(U[i * 16 + j], s[j]));
        float pr = acc.x * acc.x + acc.y * acc.y;
        fz0 += ((i >> 3) & 1) ? -pr : pr;
        fz1 += ((i >> 2) & 1) ? -pr : pr;
        fz2 += ((i >> 1) & 1) ? -pr : pr;
        fz3 += (i & 1) ? -pr : pr;
    }
    float o = head_b[0];
    o = fmaf(fz0, head_w[0], o);
    o = fmaf(fz1, head_w[1], o);
    o = fmaf(fz2, head_w[2], o);
    o = fmaf(fz3, head_w[3], o);
    o = bn_g[0] * (o - bn_m[0]) / sqrtf(bn_v[0] + 1e-5f) + bn_b[0];
    out[b] = o;
}

extern "C" void kernel_launch(void* const* d_in, const int* in_sizes, int n_in,
                              void* d_out, int out_size, void* d_ws, size_t ws_size,
                              hipStream_t stream)
{
    const float* X  = (const float*)d_in[0];
    const float* W1 = (const float*)d_in[1];
    const float* B1 = (const float*)d_in[2];
    const float* W2 = (const float*)d_in[3];
    const float* B2 = (const float*)d_in[4];
    const float* RL = (const float*)d_in[5];
    const float* QP = (const float*)d_in[6];
    const float* HW = (const float*)d_in[7];
    const float* HB = (const float*)d_in[8];
    const float* BG = (const float*)d_in[9];
    const float* BB = (const float*)d_in[10];
    const float* BM = (const float*)d_in[11];
    const float* BV = (const float*)d_in[12];
    float* out = (float*)d_out;

    OpsSpec ops;
    gen_ops_host(ops);   // deterministic, input-independent, ~µs on CPU

    const size_t H1_BYTES = (size_t)1024 * 8 * 1024 * 4;   // 33.55 MB conv1-pooled maps

    if (ws_size >= H1_BYTES + 4096) {
        float*  h1g = (float*)d_ws;
        float2* U   = (float2*)((char*)d_ws + H1_BYTES);
        unitary_kernel<<<1, 256, 0, stream>>>(ops, RL, QP, U);
        conv1_kernel<<<1024, 256, 0, stream>>>(X, W1, B1, h1g);
        conv2_head_kernel<<<1024, 256, 0, stream>>>(h1g, W2, B2, U,
                                                    HW, HB, BG, BB, BM, BV, out);
    } else {
        // fallback: Round-1 verified fused path (needs only ~66 KB of ws)
        float*  pooled = (float*)d_ws;
        float2* U      = (float2*)((char*)d_ws + 1024 * 16 * 4);
        unitary_kernel<<<1, 256, 0, stream>>>(ops, RL, QP, U);
        fused_cnn_kernel<<<1024, 256, 0, stream>>>(X, W1, B1, W2, B2, pooled);
        quantum_head_kernel<<<4, 256, 0, stream>>>(pooled, U, HW, HB, BG, BB, BM, BV, out);
    }
}